// Round 6
// baseline (214.154 us; speedup 1.0000x reference)
//
#include <hip/hip_runtime.h>
#include <hip/hip_fp16.h>

#define N_NODES 50000
#define N_EDGES 800000
#define D_IN 128
#define HH 4
#define FF 16
#define HF 64  // HH*FF
#define NCHAINS 8
#define GEMM_BLOCKS ((N_NODES + 63) / 64)  // 782

struct __align__(8) Half4 { __half2 a, b; };

// ---------------- GEMM: ft[N,64] = feat[N,128] @ W[128,64], fp16 output ----------------
// 64x64 tile per block, both operands in LDS, 4x4 register micro-tile per
// thread (16 independent FMA chains). As padded to 132 floats/row.
__global__ __launch_bounds__(256, 2) void gemm_kernel(const float* __restrict__ feat,
                                                      const float* __restrict__ W,
                                                      __half* __restrict__ fth) {
    __shared__ float As[64][132];   // ~33.8 KB feat tile (padded)
    __shared__ float Bs[D_IN][HF];  // 32 KB W

    {
        const float4* W4 = (const float4*)W;
        float4* B4 = (float4*)Bs;
#pragma unroll
        for (int i = 0; i < 8; ++i) {
            int idx = threadIdx.x + 256 * i;
            B4[idx] = W4[idx];
        }
    }
    {
        int row0 = blockIdx.x * 64;
        const float4* F4 = (const float4*)feat;
#pragma unroll
        for (int i = 0; i < 8; ++i) {
            int idx = threadIdx.x + 256 * i;  // [0,2048)
            int r = idx >> 5;
            int c4 = idx & 31;
            float4 v = make_float4(0.f, 0.f, 0.f, 0.f);
            int row = row0 + r;
            if (row < N_NODES) v = F4[(size_t)row * 32 + c4];
            *(float4*)&As[r][c4 * 4] = v;
        }
    }
    __syncthreads();

    const int tr = threadIdx.x >> 4;
    const int tc = threadIdx.x & 15;

    float acc[4][4] = {};
#pragma unroll 8
    for (int k = 0; k < D_IN; k += 4) {
        float av[4][4], bv[4][4];
#pragma unroll
        for (int i = 0; i < 4; ++i) {
            float4 a = *(const float4*)&As[tr * 4 + i][k];
            av[i][0] = a.x; av[i][1] = a.y; av[i][2] = a.z; av[i][3] = a.w;
        }
#pragma unroll
        for (int j = 0; j < 4; ++j) {
            float4 b = *(const float4*)&Bs[k + j][tc * 4];
            bv[j][0] = b.x; bv[j][1] = b.y; bv[j][2] = b.z; bv[j][3] = b.w;
        }
#pragma unroll
        for (int i = 0; i < 4; ++i)
#pragma unroll
            for (int j = 0; j < 4; ++j)
#pragma unroll
                for (int c = 0; c < 4; ++c)
                    acc[i][c] = fmaf(av[i][j], bv[j][c], acc[i][c]);
    }

    int row0 = blockIdx.x * 64;
#pragma unroll
    for (int i = 0; i < 4; ++i) {
        int row = row0 + tr * 4 + i;
        if (row < N_NODES) {
            Half4 h;
            h.a = __floats2half2_rn(acc[i][0], acc[i][1]);
            h.b = __floats2half2_rn(acc[i][2], acc[i][3]);
            *(Half4*)&fth[(size_t)row * HF + tc * 4] = h;
        }
    }
}

// ---------------- build per-node linked lists (8 chains per node) ----------------
// next2[i] = {next edge id in this chain, src[i]} -- written COALESCED.
// Only the 1.6 MB head[] takes random atomics (atomicExch, no dependent store).
__global__ __launch_bounds__(256) void build_kernel(const int* __restrict__ src,
                                                    const int* __restrict__ dst,
                                                    int* __restrict__ head,
                                                    int2* __restrict__ next2) {
    int i = blockIdx.x * 256 + threadIdx.x;
    if (i >= N_EDGES) return;
    int d = dst[i];
    int s = src[i];
    int old = atomicExch(&head[d * NCHAINS + (i & (NCHAINS - 1))], i);
    next2[i] = make_int2(old, s);
}

// ---------------- fused gather: one wave per destination node ----------------
// lane l <-> (h = l/16, f = l%16). Walks the node's 8 chains concurrently
// (8-deep MLP on the pointer chase; exhausted chains predicated to cached
// index 0 with weight 0). Softmax without max-subtraction (scores bounded:
// |e| <= |ft_s||ft_d|/4, exp stays in fp32 range). ft is fp16 (2 lines/row).
__global__ __launch_bounds__(256) void gather_kernel(const __half* __restrict__ fth,
                                                     const int* __restrict__ head,
                                                     const int2* __restrict__ next2,
                                                     float* __restrict__ out) {
    int node = __builtin_amdgcn_readfirstlane(blockIdx.x * 4 + (threadIdx.x >> 6));
    int lane = threadIdx.x & 63;

    float ftd = __half2float(fth[(size_t)node * HF + lane]);

    int c[NCHAINS];
#pragma unroll
    for (int j = 0; j < NCHAINS; ++j) c[j] = head[node * NCHAINS + j];

    float acc = 0.0f, l = 0.0f;

    while (true) {
        int all = c[0];
#pragma unroll
        for (int j = 1; j < NCHAINS; ++j) all &= c[j];
        if (all == -1) break;  // every chain at -1 (only -1 keeps all sign bits)

        bool a[NCHAINS];
        int2 n[NCHAINS];
        float v[NCHAINS];
#pragma unroll
        for (int j = 0; j < NCHAINS; ++j) {
            a[j] = c[j] >= 0;
            n[j] = next2[a[j] ? c[j] : 0];
        }
#pragma unroll
        for (int j = 0; j < NCHAINS; ++j)
            v[j] = __half2float(fth[(size_t)n[j].y * HF + lane]);

        float p[NCHAINS];
#pragma unroll
        for (int j = 0; j < NCHAINS; ++j) p[j] = ftd * v[j];
#pragma unroll
        for (int j = 0; j < NCHAINS; ++j) p[j] += __shfl_xor(p[j], 1, 64);
#pragma unroll
        for (int j = 0; j < NCHAINS; ++j) p[j] += __shfl_xor(p[j], 2, 64);
#pragma unroll
        for (int j = 0; j < NCHAINS; ++j) p[j] += __shfl_xor(p[j], 4, 64);
#pragma unroll
        for (int j = 0; j < NCHAINS; ++j) p[j] += __shfl_xor(p[j], 8, 64);

#pragma unroll
        for (int j = 0; j < NCHAINS; ++j) {
            float w = a[j] ? __expf(p[j] * 0.25f) : 0.0f;
            acc = fmaf(w, v[j], acc);
            l += w;
            c[j] = a[j] ? n[j].x : -1;
        }
    }

    out[(size_t)node * HF + lane] = (l > 0.0f) ? acc / l : 0.0f;
}

extern "C" void kernel_launch(void* const* d_in, const int* in_sizes, int n_in,
                              void* d_out, int out_size, void* d_ws, size_t ws_size,
                              hipStream_t stream) {
    const float* feat = (const float*)d_in[0];
    const float* W = (const float*)d_in[1];
    const int* src = (const int*)d_in[2];
    const int* dst = (const int*)d_in[3];
    float* out = (float*)d_out;

    // workspace layout
    __half* fth = (__half*)d_ws;                           // N*64 halves (6.4 MB)
    int* head = (int*)(fth + (size_t)N_NODES * HF);        // N*8 ints    (1.6 MB)
    int2* next2 = (int2*)(head + N_NODES * NCHAINS);       // E int2      (6.4 MB)

    hipMemsetAsync(head, 0xFF, (size_t)N_NODES * NCHAINS * sizeof(int), stream);  // -1
    gemm_kernel<<<GEMM_BLOCKS, 256, 0, stream>>>(feat, W, fth);
    build_kernel<<<(N_EDGES + 255) / 256, 256, 0, stream>>>(src, dst, head, next2);
    gather_kernel<<<N_NODES * 64 / 256, 256, 0, stream>>>(fth, head, next2, out);
}

// Round 7
// 157.072 us; speedup vs baseline: 1.3634x; 1.3634x over previous
//
#include <hip/hip_runtime.h>
#include <hip/hip_fp16.h>

#define N_NODES 50000
#define N_EDGES 800000
#define D_IN 128
#define HH 4
#define FF 16
#define HF 64  // HH*FF
#define NBUCKETS 196                 // ceil(N_NODES/256); bucket b covers dst in [b*256, b*256+256)
#define BCAP 4608                    // bucket capacity; Poisson(4096)+8 sigma
#define CHUNK 2048                   // edges per bin_kernel block
#define NBIN_BLOCKS ((N_EDGES + CHUNK - 1) / CHUNK)  // 391
#define GEMM_BLOCKS ((N_NODES + 63) / 64)            // 782

struct __align__(8) Half4 { __half2 a, b; };

// ---------------- GEMM: ft[N,64] = feat[N,128] @ W[128,64], fp16 output ----------------
__global__ __launch_bounds__(256, 2) void gemm_kernel(const float* __restrict__ feat,
                                                      const float* __restrict__ W,
                                                      __half* __restrict__ fth) {
    __shared__ float As[64][132];   // padded: row stride 132 breaks 4-way bank conflict
    __shared__ float Bs[D_IN][HF];

    {
        const float4* W4 = (const float4*)W;
        float4* B4 = (float4*)Bs;
#pragma unroll
        for (int i = 0; i < 8; ++i) {
            int idx = threadIdx.x + 256 * i;
            B4[idx] = W4[idx];
        }
    }
    {
        int row0 = blockIdx.x * 64;
        const float4* F4 = (const float4*)feat;
#pragma unroll
        for (int i = 0; i < 8; ++i) {
            int idx = threadIdx.x + 256 * i;
            int r = idx >> 5;
            int c4 = idx & 31;
            float4 v = make_float4(0.f, 0.f, 0.f, 0.f);
            int row = row0 + r;
            if (row < N_NODES) v = F4[(size_t)row * 32 + c4];
            *(float4*)&As[r][c4 * 4] = v;
        }
    }
    __syncthreads();

    const int tr = threadIdx.x >> 4;
    const int tc = threadIdx.x & 15;

    float acc[4][4] = {};
#pragma unroll 8
    for (int k = 0; k < D_IN; k += 4) {
        float av[4][4], bv[4][4];
#pragma unroll
        for (int i = 0; i < 4; ++i) {
            float4 a = *(const float4*)&As[tr * 4 + i][k];
            av[i][0] = a.x; av[i][1] = a.y; av[i][2] = a.z; av[i][3] = a.w;
        }
#pragma unroll
        for (int j = 0; j < 4; ++j) {
            float4 b = *(const float4*)&Bs[k + j][tc * 4];
            bv[j][0] = b.x; bv[j][1] = b.y; bv[j][2] = b.z; bv[j][3] = b.w;
        }
#pragma unroll
        for (int i = 0; i < 4; ++i)
#pragma unroll
            for (int j = 0; j < 4; ++j)
#pragma unroll
                for (int c = 0; c < 4; ++c)
                    acc[i][c] = fmaf(av[i][j], bv[j][c], acc[i][c]);
    }

    int row0 = blockIdx.x * 64;
#pragma unroll
    for (int i = 0; i < 4; ++i) {
        int row = row0 + tr * 4 + i;
        if (row < N_NODES) {
            Half4 h;
            h.a = __floats2half2_rn(acc[i][0], acc[i][1]);
            h.b = __floats2half2_rn(acc[i][2], acc[i][3]);
            *(Half4*)&fth[(size_t)row * HF + tc * 4] = h;
        }
    }
}

// ---------------- pass 1: bin edges into 196 dst-buckets (LDS counting sort) ----------------
// rec = src | (dst&255)<<16 (both fit 16/8 bits). Per-block LDS sort, then chunked
// flush: one global atomicAdd per (block,bucket), ~10 contiguous ints per flush ->
// write lines fill densely (no 16x line-writeback amplification).
__global__ __launch_bounds__(256) void bin_kernel(const int* __restrict__ src,
                                                  const int* __restrict__ dst,
                                                  int* __restrict__ gcur,
                                                  int* __restrict__ recs) {
    __shared__ int hist[256];
    __shared__ int offs[256];
    __shared__ int cur[256];
    __shared__ int lrec[CHUNK];

    int tid = threadIdx.x;
    int e0 = blockIdx.x * CHUNK;
    int n = N_EDGES - e0; if (n > CHUNK) n = CHUNK;

    hist[tid] = 0;
    __syncthreads();

    int myrec[CHUNK / 256];
    int myb[CHUNK / 256];
#pragma unroll
    for (int k = 0; k < CHUNK / 256; ++k) {
        int idx = tid + k * 256;
        myb[k] = -1;
        if (idx < n) {
            int s = src[e0 + idx];
            int d = dst[e0 + idx];
            int b = d >> 8;
            myrec[k] = s | ((d & 255) << 16);
            myb[k] = b;
            atomicAdd(&hist[b], 1);
        }
    }
    __syncthreads();

    // exclusive scan of hist over 256 entries (Hillis-Steele)
    int val = hist[tid];
    offs[tid] = val;
    __syncthreads();
#pragma unroll
    for (int off = 1; off < 256; off <<= 1) {
        int t = (tid >= off) ? offs[tid - off] : 0;
        __syncthreads();
        offs[tid] += t;
        __syncthreads();
    }
    int excl = offs[tid] - val;
    __syncthreads();
    offs[tid] = excl;
    cur[tid] = excl;
    __syncthreads();

#pragma unroll
    for (int k = 0; k < CHUNK / 256; ++k) {
        if (myb[k] >= 0) {
            int p = atomicAdd(&cur[myb[k]], 1);
            lrec[p] = myrec[k];
        }
    }
    __syncthreads();

    // chunked flush: thread tid owns bucket tid
    if (tid < NBUCKETS) {
        int c = hist[tid];
        if (c > 0) {
            int g = atomicAdd(&gcur[tid], c);
            if (g + c > BCAP) c = (BCAP > g) ? (BCAP - g) : 0;  // impossible-tail guard
            int lo = offs[tid];
            int* dp = recs + (size_t)tid * BCAP + g;
            for (int i = 0; i < c; ++i) dp[i] = lrec[lo + i];
        }
    }
}

// ---------------- pass 2: per-bucket counting sort -> CSR (coalesced writes) ----------------
__global__ __launch_bounds__(256) void sort_kernel(const int* __restrict__ gcur,
                                                   const int* __restrict__ recs,
                                                   int* __restrict__ csr,
                                                   int* __restrict__ row_beg,
                                                   int* __restrict__ row_end) {
    __shared__ int lhist[256];
    __shared__ int loffs[256];
    __shared__ int lcur[256];
    __shared__ int sorted[BCAP];  // 18 KB

    int tid = threadIdx.x;
    int b = blockIdx.x;
    int cnt = gcur[b]; if (cnt > BCAP) cnt = BCAP;
    const int* rp = recs + (size_t)b * BCAP;

    lhist[tid] = 0;
    __syncthreads();
    for (int i = tid; i < cnt; i += 256) atomicAdd(&lhist[rp[i] >> 16], 1);
    __syncthreads();

    int val = lhist[tid];
    loffs[tid] = val;
    __syncthreads();
#pragma unroll
    for (int off = 1; off < 256; off <<= 1) {
        int t = (tid >= off) ? loffs[tid - off] : 0;
        __syncthreads();
        loffs[tid] += t;
        __syncthreads();
    }
    int excl = loffs[tid] - val;
    __syncthreads();
    loffs[tid] = excl;
    lcur[tid] = excl;
    __syncthreads();

    for (int i = tid; i < cnt; i += 256) {
        int rec = rp[i];
        int p = atomicAdd(&lcur[rec >> 16], 1);
        sorted[p] = rec & 0xFFFF;  // src id
    }
    __syncthreads();

    int base = b * BCAP;
    for (int i = tid; i < cnt; i += 256) csr[base + i] = sorted[i];

    int node = b * 256 + tid;
    if (node < N_NODES) {
        row_beg[node] = base + excl;
        row_end[node] = base + excl + val;
    }
}

// ---------------- fused gather: one wave per destination node, flat CSR ----------------
// lane l <-> (h = l/16, f = l%16). Softmax without max-subtraction (scores
// bounded, exp in fp32 range). Index loads wave-uniform -> scalar; 8 gathers
// in flight. fp16 ft halves the random-gather line traffic.
__global__ __launch_bounds__(256) void gather_kernel(const __half* __restrict__ fth,
                                                     const int* __restrict__ row_beg,
                                                     const int* __restrict__ row_end,
                                                     const int* __restrict__ csr,
                                                     float* __restrict__ out) {
    int node = __builtin_amdgcn_readfirstlane(blockIdx.x * 4 + (threadIdx.x >> 6));
    int lane = threadIdx.x & 63;

    int beg = row_beg[node];
    int end = row_end[node];

    float ftd = __half2float(fth[(size_t)node * HF + lane]);
    float acc = 0.0f, l = 0.0f;

    int i = beg;
    for (; i + 8 <= end; i += 8) {
        int s[8];
        float v[8];
#pragma unroll
        for (int j = 0; j < 8; ++j) s[j] = csr[i + j];
#pragma unroll
        for (int j = 0; j < 8; ++j) v[j] = __half2float(fth[(size_t)s[j] * HF + lane]);
#pragma unroll
        for (int j = 0; j < 8; ++j) {
            float p = ftd * v[j];
            p += __shfl_xor(p, 1, 64);
            p += __shfl_xor(p, 2, 64);
            p += __shfl_xor(p, 4, 64);
            p += __shfl_xor(p, 8, 64);
            float w = __expf(p * 0.25f);
            acc = fmaf(w, v[j], acc);
            l += w;
        }
    }
    for (; i + 4 <= end; i += 4) {
        int s[4];
        float v[4];
#pragma unroll
        for (int j = 0; j < 4; ++j) s[j] = csr[i + j];
#pragma unroll
        for (int j = 0; j < 4; ++j) v[j] = __half2float(fth[(size_t)s[j] * HF + lane]);
#pragma unroll
        for (int j = 0; j < 4; ++j) {
            float p = ftd * v[j];
            p += __shfl_xor(p, 1, 64);
            p += __shfl_xor(p, 2, 64);
            p += __shfl_xor(p, 4, 64);
            p += __shfl_xor(p, 8, 64);
            float w = __expf(p * 0.25f);
            acc = fmaf(w, v[j], acc);
            l += w;
        }
    }
    for (; i < end; ++i) {
        int s = csr[i];
        float v = __half2float(fth[(size_t)s * HF + lane]);
        float p = ftd * v;
        p += __shfl_xor(p, 1, 64);
        p += __shfl_xor(p, 2, 64);
        p += __shfl_xor(p, 4, 64);
        p += __shfl_xor(p, 8, 64);
        float w = __expf(p * 0.25f);
        acc = fmaf(w, v, acc);
        l += w;
    }

    out[(size_t)node * HF + lane] = (l > 0.0f) ? acc / l : 0.0f;
}

extern "C" void kernel_launch(void* const* d_in, const int* in_sizes, int n_in,
                              void* d_out, int out_size, void* d_ws, size_t ws_size,
                              hipStream_t stream) {
    const float* feat = (const float*)d_in[0];
    const float* W = (const float*)d_in[1];
    const int* src = (const int*)d_in[2];
    const int* dst = (const int*)d_in[3];
    float* out = (float*)d_out;

    // workspace layout
    __half* fth = (__half*)d_ws;                            // N*64 halves (6.4 MB)
    int* recs = (int*)(fth + (size_t)N_NODES * HF);         // NBUCKETS*BCAP ints (3.6 MB)
    int* csr = recs + (size_t)NBUCKETS * BCAP;              // NBUCKETS*BCAP ints (3.6 MB)
    int* row_beg = csr + (size_t)NBUCKETS * BCAP;           // N ints
    int* row_end = row_beg + N_NODES;                       // N ints
    int* gcur = row_end + N_NODES;                          // NBUCKETS ints

    hipMemsetAsync(gcur, 0, NBUCKETS * sizeof(int), stream);
    gemm_kernel<<<GEMM_BLOCKS, 256, 0, stream>>>(feat, W, fth);
    bin_kernel<<<NBIN_BLOCKS, 256, 0, stream>>>(src, dst, gcur, recs);
    sort_kernel<<<NBUCKETS, 256, 0, stream>>>(gcur, recs, csr, row_beg, row_end);
    gather_kernel<<<N_NODES * 64 / 256, 256, 0, stream>>>(fth, row_beg, row_end, csr, out);
}

// Round 8
// 149.052 us; speedup vs baseline: 1.4368x; 1.0538x over previous
//
#include <hip/hip_runtime.h>
#include <hip/hip_fp16.h>

#define N_NODES 50000
#define N_EDGES 800000
#define D_IN 128
#define HH 4
#define FF 16
#define HF 64  // HH*FF
#define NBUCKETS 196                 // ceil(N_NODES/256); bucket b covers dst in [b*256, b*256+256)
#define BCAP 4608                    // bucket capacity; Poisson(4096) + 8 sigma
#define CHUNK 2048                   // edges per bin_kernel block
#define NBIN_BLOCKS ((N_EDGES + CHUNK - 1) / CHUNK)  // 391
#define GEMM_BLOCKS ((N_NODES + 63) / 64)            // 782

struct __align__(8) Half4 { __half2 a, b; };

// ---------------- GEMM: ft[N,64] = feat[N,128] @ W[128,64], fp16 output ----------------
__global__ __launch_bounds__(256, 2) void gemm_kernel(const float* __restrict__ feat,
                                                      const float* __restrict__ W,
                                                      __half* __restrict__ fth) {
    __shared__ float As[64][132];   // padded: row stride 132 breaks 4-way bank conflict
    __shared__ float Bs[D_IN][HF];

    {
        const float4* W4 = (const float4*)W;
        float4* B4 = (float4*)Bs;
#pragma unroll
        for (int i = 0; i < 8; ++i) {
            int idx = threadIdx.x + 256 * i;
            B4[idx] = W4[idx];
        }
    }
    {
        int row0 = blockIdx.x * 64;
        const float4* F4 = (const float4*)feat;
#pragma unroll
        for (int i = 0; i < 8; ++i) {
            int idx = threadIdx.x + 256 * i;
            int r = idx >> 5;
            int c4 = idx & 31;
            float4 v = make_float4(0.f, 0.f, 0.f, 0.f);
            int row = row0 + r;
            if (row < N_NODES) v = F4[(size_t)row * 32 + c4];
            *(float4*)&As[r][c4 * 4] = v;
        }
    }
    __syncthreads();

    const int tr = threadIdx.x >> 4;
    const int tc = threadIdx.x & 15;

    float acc[4][4] = {};
#pragma unroll 8
    for (int k = 0; k < D_IN; k += 4) {
        float av[4][4], bv[4][4];
#pragma unroll
        for (int i = 0; i < 4; ++i) {
            float4 a = *(const float4*)&As[tr * 4 + i][k];
            av[i][0] = a.x; av[i][1] = a.y; av[i][2] = a.z; av[i][3] = a.w;
        }
#pragma unroll
        for (int j = 0; j < 4; ++j) {
            float4 b = *(const float4*)&Bs[k + j][tc * 4];
            bv[j][0] = b.x; bv[j][1] = b.y; bv[j][2] = b.z; bv[j][3] = b.w;
        }
#pragma unroll
        for (int i = 0; i < 4; ++i)
#pragma unroll
            for (int j = 0; j < 4; ++j)
#pragma unroll
                for (int c = 0; c < 4; ++c)
                    acc[i][c] = fmaf(av[i][j], bv[j][c], acc[i][c]);
    }

    int row0 = blockIdx.x * 64;
#pragma unroll
    for (int i = 0; i < 4; ++i) {
        int row = row0 + tr * 4 + i;
        if (row < N_NODES) {
            Half4 h;
            h.a = __floats2half2_rn(acc[i][0], acc[i][1]);
            h.b = __floats2half2_rn(acc[i][2], acc[i][3]);
            *(Half4*)&fth[(size_t)row * HF + tc * 4] = h;
        }
    }
}

// ---------------- pass 1: bin edges into 196 dst-buckets ----------------
// rec = src(16b) | (dst&255)<<16 | bucket<<24. LDS counting sort per block,
// then fully block-parallel flush (bucket id recovered from the rec itself).
__global__ __launch_bounds__(256) void bin_kernel(const int* __restrict__ src,
                                                  const int* __restrict__ dst,
                                                  int* __restrict__ gcur,
                                                  int* __restrict__ recs) {
    __shared__ int hist[256];
    __shared__ int offs[256];
    __shared__ int cur[256];
    __shared__ int gbase[256];
    __shared__ int lrec[CHUNK];

    int tid = threadIdx.x;
    int e0 = blockIdx.x * CHUNK;
    int n = N_EDGES - e0; if (n > CHUNK) n = CHUNK;

    hist[tid] = 0;
    __syncthreads();

    int myrec[CHUNK / 256];
    int myb[CHUNK / 256];
#pragma unroll
    for (int k = 0; k < CHUNK / 256; ++k) {
        int idx = tid + k * 256;
        myb[k] = -1;
        if (idx < n) {
            int s = src[e0 + idx];
            int d = dst[e0 + idx];
            int b = d >> 8;
            myrec[k] = s | ((d & 255) << 16) | (b << 24);
            myb[k] = b;
            atomicAdd(&hist[b], 1);
        }
    }
    __syncthreads();

    // exclusive scan of hist (Hillis-Steele over 256)
    int val = hist[tid];
    offs[tid] = val;
    __syncthreads();
#pragma unroll
    for (int off = 1; off < 256; off <<= 1) {
        int t = (tid >= off) ? offs[tid - off] : 0;
        __syncthreads();
        offs[tid] += t;
        __syncthreads();
    }
    int excl = offs[tid] - val;
    __syncthreads();
    offs[tid] = excl;
    cur[tid] = excl;
    if (tid < NBUCKETS && val > 0) gbase[tid] = atomicAdd(&gcur[tid], val);
    __syncthreads();

#pragma unroll
    for (int k = 0; k < CHUNK / 256; ++k) {
        if (myb[k] >= 0) {
            int p = atomicAdd(&cur[myb[k]], 1);
            lrec[p] = myrec[k];
        }
    }
    __syncthreads();

    // parallel flush: bucket id is in the record
    for (int i = tid; i < n; i += 256) {
        int r = lrec[i];
        int b = (r >> 24) & 255;
        int pos = gbase[b] + (i - offs[b]);
        if (pos < BCAP) recs[(size_t)b * BCAP + pos] = r;
    }
}

// ---------------- pass 2: per-bucket counting sort -> CSR ----------------
// Scatters src ids straight to the bucket's 18 KB global window (L2-hot).
__global__ __launch_bounds__(256) void sort_kernel(const int* __restrict__ gcur,
                                                   const int* __restrict__ recs,
                                                   int* __restrict__ csr,
                                                   int* __restrict__ row_beg,
                                                   int* __restrict__ row_end) {
    __shared__ int lhist[256];
    __shared__ int loffs[256];
    __shared__ int lcur[256];

    int tid = threadIdx.x;
    int b = blockIdx.x;
    int cnt = gcur[b]; if (cnt > BCAP) cnt = BCAP;
    const int* rp = recs + (size_t)b * BCAP;

    lhist[tid] = 0;
    __syncthreads();
    for (int i = tid; i < cnt; i += 256) atomicAdd(&lhist[(rp[i] >> 16) & 255], 1);
    __syncthreads();

    int val = lhist[tid];
    loffs[tid] = val;
    __syncthreads();
#pragma unroll
    for (int off = 1; off < 256; off <<= 1) {
        int t = (tid >= off) ? loffs[tid - off] : 0;
        __syncthreads();
        loffs[tid] += t;
        __syncthreads();
    }
    int excl = loffs[tid] - val;
    __syncthreads();
    lcur[tid] = excl;
    __syncthreads();

    int base = b * BCAP;
    for (int i = tid; i < cnt; i += 256) {
        int rec = rp[i];
        int p = atomicAdd(&lcur[(rec >> 16) & 255], 1);
        csr[base + p] = rec & 0xFFFF;  // src id
    }

    int node = b * 256 + tid;
    if (node < N_NODES) {
        row_beg[node] = base + excl;
        row_end[node] = base + excl + val;
    }
}

// ---------------- fused gather: one wave per node, TWO edges per iteration ----------------
// lane layout: bit5 selects edge (A = lanes 0-31, B = lanes 32-63); lanes hl=lane&31
// each hold features {2hl, 2hl+1} as __half2. A head = 16 features = 8 lanes, so the
// per-head dot needs only 3 shfl_xor (1,2,4) -- 1.5 DS ops/edge vs 4 before.
// Softmax without max-subtraction (scores bounded, exp in fp32 range).
__global__ __launch_bounds__(256) void gather_kernel(const __half* __restrict__ fth,
                                                     const int* __restrict__ row_beg,
                                                     const int* __restrict__ row_end,
                                                     const int* __restrict__ csr,
                                                     float* __restrict__ out) {
    int node = __builtin_amdgcn_readfirstlane(blockIdx.x * 4 + (threadIdx.x >> 6));
    int lane = threadIdx.x & 63;
    int hl = lane & 31;          // feature-pair index
    bool hi = lane >= 32;        // B-edge half

    int beg = row_beg[node];
    int end = row_end[node];

    __half2 ftd2 = *(const __half2*)&fth[(size_t)node * HF + 2 * hl];

    float acc0 = 0.0f, acc1 = 0.0f, lsum = 0.0f;

    int i = beg;
    // 2 pairs (4 edges) per iteration for MLP
    for (; i + 4 <= end; i += 4) {
        int sA0 = csr[i + 0], sB0 = csr[i + 1];
        int sA1 = csr[i + 2], sB1 = csr[i + 3];
        int s0 = hi ? sB0 : sA0;
        int s1 = hi ? sB1 : sA1;
        __half2 v20 = *(const __half2*)&fth[(size_t)s0 * HF + 2 * hl];
        __half2 v21 = *(const __half2*)&fth[(size_t)s1 * HF + 2 * hl];

        __half2 pr0 = __hmul2(ftd2, v20);
        __half2 pr1 = __hmul2(ftd2, v21);
        float p0 = __low2float(pr0) + __high2float(pr0);
        float p1 = __low2float(pr1) + __high2float(pr1);
        p0 += __shfl_xor(p0, 1, 64); p1 += __shfl_xor(p1, 1, 64);
        p0 += __shfl_xor(p0, 2, 64); p1 += __shfl_xor(p1, 2, 64);
        p0 += __shfl_xor(p0, 4, 64); p1 += __shfl_xor(p1, 4, 64);
        float w0 = __expf(p0 * 0.25f);
        float w1 = __expf(p1 * 0.25f);
        acc0 = fmaf(w0, __low2float(v20), acc0);
        acc1 = fmaf(w0, __high2float(v20), acc1);
        acc0 = fmaf(w1, __low2float(v21), acc0);
        acc1 = fmaf(w1, __high2float(v21), acc1);
        lsum += w0 + w1;
    }
    // tail pairs (possibly odd final edge)
    for (; i < end; i += 2) {
        bool hasB = (i + 1 < end);
        int sA = csr[i];
        int sB = hasB ? csr[i + 1] : sA;
        int s = hi ? sB : sA;
        __half2 v2 = *(const __half2*)&fth[(size_t)s * HF + 2 * hl];
        __half2 pr = __hmul2(ftd2, v2);
        float p = __low2float(pr) + __high2float(pr);
        p += __shfl_xor(p, 1, 64);
        p += __shfl_xor(p, 2, 64);
        p += __shfl_xor(p, 4, 64);
        float w = __expf(p * 0.25f);
        if (hi && !hasB) w = 0.0f;
        acc0 = fmaf(w, __low2float(v2), acc0);
        acc1 = fmaf(w, __high2float(v2), acc1);
        lsum += w;
    }

    // combine A/B halves (lane and lane^32 hold the same features)
    acc0 += __shfl_xor(acc0, 32, 64);
    acc1 += __shfl_xor(acc1, 32, 64);
    lsum += __shfl_xor(lsum, 32, 64);

    if (!hi) {
        float inv = (lsum > 0.0f) ? 1.0f / lsum : 0.0f;
        *(float2*)&out[(size_t)node * HF + 2 * hl] = make_float2(acc0 * inv, acc1 * inv);
    }
}

extern "C" void kernel_launch(void* const* d_in, const int* in_sizes, int n_in,
                              void* d_out, int out_size, void* d_ws, size_t ws_size,
                              hipStream_t stream) {
    const float* feat = (const float*)d_in[0];
    const float* W = (const float*)d_in[1];
    const int* src = (const int*)d_in[2];
    const int* dst = (const int*)d_in[3];
    float* out = (float*)d_out;

    // workspace layout
    __half* fth = (__half*)d_ws;                            // N*64 halves (6.4 MB)
    int* recs = (int*)(fth + (size_t)N_NODES * HF);         // NBUCKETS*BCAP ints (3.6 MB)
    int* csr = recs + (size_t)NBUCKETS * BCAP;              // NBUCKETS*BCAP ints (3.6 MB)
    int* row_beg = csr + (size_t)NBUCKETS * BCAP;           // N ints
    int* row_end = row_beg + N_NODES;                       // N ints
    int* gcur = row_end + N_NODES;                          // NBUCKETS ints

    hipMemsetAsync(gcur, 0, NBUCKETS * sizeof(int), stream);
    gemm_kernel<<<GEMM_BLOCKS, 256, 0, stream>>>(feat, W, fth);
    bin_kernel<<<NBIN_BLOCKS, 256, 0, stream>>>(src, dst, gcur, recs);
    sort_kernel<<<NBUCKETS, 256, 0, stream>>>(gcur, recs, csr, row_beg, row_end);
    gather_kernel<<<N_NODES * 64 / 256, 256, 0, stream>>>(fth, row_beg, row_end, csr, out);
}